// Round 1
// baseline (663.287 us; speedup 1.0000x reference)
//
#include <hip/hip_runtime.h>
#include <math.h>

#define NQ 512
#define NC 65536
#define DIM 768
#define QREC 72

// ---------------------------------------------------------------------------
// acos via A&S 4.4.46 polynomial (|err| <= 2e-8 abs): acos(x) for x in [0,1]
// = sqrt(1-x) * poly(x); x<0 -> pi - acos(-x). Branchless select.
// ---------------------------------------------------------------------------
__device__ __forceinline__ float acos_poly(float x) {
  float z = fabsf(x);
  float p = -0.0012624911f;
  p = fmaf(p, z, 0.0066700901f);
  p = fmaf(p, z, -0.0170881256f);
  p = fmaf(p, z, 0.0308918810f);
  p = fmaf(p, z, -0.0501743046f);
  p = fmaf(p, z, 0.0889789874f);
  p = fmaf(p, z, -0.2145988016f);
  p = fmaf(p, z, 1.5707963050f);
  float r = sqrtf(1.0f - z) * p;
  return (x < 0.0f) ? (3.14159265358979f - r) : r;
}

// ---------------------------------------------------------------------------
// Query-side projection + softplus MLP weights. One block (128 thr) per query.
// Record layout (stride QREC=72 floats):
//   [0:32) e (unit), [32:48) s (unit), [48:64) h (expmap0),
//   [64] xn=|h|^2, [65] beta=1-xn, [66:69) w0,w1,w2
// ---------------------------------------------------------------------------
__global__ __launch_bounds__(128) void proj_q(
    const float* __restrict__ xq,
    const float* __restrict__ We, const float* __restrict__ be,
    const float* __restrict__ Wh, const float* __restrict__ bh,
    const float* __restrict__ Ws, const float* __restrict__ bs,
    const float* __restrict__ shp,
    const float* __restrict__ W1, const float* __restrict__ b1,
    const float* __restrict__ W2, const float* __restrict__ b2,
    float* __restrict__ qrec)
{
  __shared__ float xrow[DIM];
  __shared__ float vals[96];
  __shared__ float reluv[32];
  __shared__ float hv[16];
  __shared__ float stats[8]; // ne, ns, xn, beta, w0, w1, w2
  const int t = threadIdx.x;
  const int q = blockIdx.x;

  for (int i = t; i < DIM; i += 128) xrow[i] = xq[(size_t)q * DIM + i];
  __syncthreads();

  if (t < 96) {
    const float* wr;
    float bias;
    if (t < 32)      { wr = We + (size_t)t * DIM;        bias = be[t]; }
    else if (t < 48) { wr = Ws + (size_t)(t - 32) * DIM; bias = bs[t - 32]; }
    else if (t < 64) { wr = Wh + (size_t)(t - 48) * DIM; bias = bh[t - 48]; }
    else             { wr = W1 + (size_t)(t - 64) * DIM; bias = b1[t - 64]; }
    float acc = 0.0f;
    for (int k = 0; k < DIM; ++k) acc = fmaf(xrow[k], wr[k], acc);
    acc += bias;
    if (t >= 48 && t < 64) acc *= shp[0];  // scale_h on the hyperbolic branch
    vals[t] = acc;
  }
  __syncthreads();
  if (t < 32) reluv[t] = fmaxf(vals[64 + t], 0.0f);
  __syncthreads();

  if (t == 0) {
    float s = 0.0f;
    for (int j = 0; j < 32; ++j) s += vals[j] * vals[j];
    stats[0] = sqrtf(s);
  } else if (t == 1) {
    float s = 0.0f;
    for (int j = 32; j < 48; ++j) s += vals[j] * vals[j];
    stats[1] = sqrtf(s);
  } else if (t == 2) {
    float s = 0.0f;
    for (int j = 48; j < 64; ++j) s += vals[j] * vals[j];
    float n = fmaxf(sqrtf(s), 1e-15f);
    float f = tanhf(n) / n;
    float xn = 0.0f;
    for (int j = 0; j < 16; ++j) {
      float hj = vals[48 + j] * f;
      hv[j] = hj;
      xn += hj * hj;
    }
    stats[2] = xn;
    stats[3] = 1.0f - xn;
  } else if (t >= 3 && t < 6) {
    int m = t - 3;
    float s = 0.0f;
    for (int j = 0; j < 32; ++j) s = fmaf(reluv[j], W2[m * 32 + j], s);
    s += b2[m];
    // stable softplus
    stats[4 + m] = fmaxf(s, 0.0f) + log1pf(expf(-fabsf(s)));
  }
  __syncthreads();

  float* rec = qrec + (size_t)q * QREC;
  if (t < 32)       rec[t] = vals[t] / stats[0];
  else if (t < 48)  rec[t] = vals[t] / stats[1];
  else if (t < 64)  rec[t] = hv[t - 48];
  else if (t == 64) rec[64] = stats[2];
  else if (t == 65) rec[65] = stats[3];
  else if (t >= 66 && t < 69) rec[t] = stats[4 + (t - 66)];
}

// ---------------------------------------------------------------------------
// Corpus projection: [NC,768] @ [768,64] -> SoA ce[32][NC], cs[16][NC],
// ch[16][NC], cyn[NC]. Tile: 64 rows x 64 outs per block (256 thr),
// 4x4 register blocking, k-chunk 32 staged transposed in LDS.
// Out order: 0..31 = e, 32..47 = s, 48..63 = h.
// ---------------------------------------------------------------------------
__global__ __launch_bounds__(256) void proj_corpus(
    const float* __restrict__ xc,
    const float* __restrict__ We, const float* __restrict__ be,
    const float* __restrict__ Wh, const float* __restrict__ bh,
    const float* __restrict__ Ws, const float* __restrict__ bs,
    const float* __restrict__ shp,
    float* __restrict__ ce, float* __restrict__ cs,
    float* __restrict__ ch, float* __restrict__ cyn)
{
  __shared__ float lx[32][68];   // [k][row], padded for staging-write banks
  __shared__ float lw[32][68];   // [k][out]
  __shared__ float vals[64][65]; // raw projections, padded for row reads

  const int tid = threadIdx.x;
  const int r0 = blockIdx.x * 64;
  const int oq = tid & 15;   // out quad: outs 4*oq..4*oq+3
  const int rq = tid >> 4;   // row quad: rows 4*rq..4*rq+3

  float acc[4][4]; // [oi][ri]
  #pragma unroll
  for (int a = 0; a < 4; ++a)
    #pragma unroll
    for (int b = 0; b < 4; ++b) acc[a][b] = 0.0f;

  for (int k0 = 0; k0 < DIM; k0 += 32) {
    // stage X chunk transposed: 64 rows x 32 k
    #pragma unroll
    for (int i = 0; i < 2; ++i) {
      int lid = tid + 256 * i;   // 0..511
      int row = lid >> 3;        // 0..63
      int kq = lid & 7;          // 0..7
      const float4 v = *(const float4*)(xc + (size_t)(r0 + row) * DIM + k0 + 4 * kq);
      lx[4 * kq + 0][row] = v.x;
      lx[4 * kq + 1][row] = v.y;
      lx[4 * kq + 2][row] = v.z;
      lx[4 * kq + 3][row] = v.w;
    }
    // stage W chunk transposed (row select: e / s / h)
    #pragma unroll
    for (int i = 0; i < 2; ++i) {
      int lid = tid + 256 * i;
      int o = lid >> 3;
      int kq = lid & 7;
      const float* wrow = (o < 32) ? (We + (size_t)o * DIM)
                        : (o < 48) ? (Ws + (size_t)(o - 32) * DIM)
                                   : (Wh + (size_t)(o - 48) * DIM);
      const float4 v = *(const float4*)(wrow + k0 + 4 * kq);
      lw[4 * kq + 0][o] = v.x;
      lw[4 * kq + 1][o] = v.y;
      lw[4 * kq + 2][o] = v.z;
      lw[4 * kq + 3][o] = v.w;
    }
    __syncthreads();
    #pragma unroll
    for (int k = 0; k < 32; ++k) {
      const float4 wv = *(const float4*)&lw[k][4 * oq];
      const float4 xv = *(const float4*)&lx[k][4 * rq];
      acc[0][0] = fmaf(wv.x, xv.x, acc[0][0]);
      acc[0][1] = fmaf(wv.x, xv.y, acc[0][1]);
      acc[0][2] = fmaf(wv.x, xv.z, acc[0][2]);
      acc[0][3] = fmaf(wv.x, xv.w, acc[0][3]);
      acc[1][0] = fmaf(wv.y, xv.x, acc[1][0]);
      acc[1][1] = fmaf(wv.y, xv.y, acc[1][1]);
      acc[1][2] = fmaf(wv.y, xv.z, acc[1][2]);
      acc[1][3] = fmaf(wv.y, xv.w, acc[1][3]);
      acc[2][0] = fmaf(wv.z, xv.x, acc[2][0]);
      acc[2][1] = fmaf(wv.z, xv.y, acc[2][1]);
      acc[2][2] = fmaf(wv.z, xv.z, acc[2][2]);
      acc[2][3] = fmaf(wv.z, xv.w, acc[2][3]);
      acc[3][0] = fmaf(wv.w, xv.x, acc[3][0]);
      acc[3][1] = fmaf(wv.w, xv.y, acc[3][1]);
      acc[3][2] = fmaf(wv.w, xv.z, acc[3][2]);
      acc[3][3] = fmaf(wv.w, xv.w, acc[3][3]);
    }
    __syncthreads();
  }

  // bias + scale, park raw projections in LDS
  const float sh = shp[0];
  #pragma unroll
  for (int oi = 0; oi < 4; ++oi) {
    int o = 4 * oq + oi;
    float bias = (o < 32) ? be[o] : (o < 48) ? bs[o - 32] : bh[o - 48];
    #pragma unroll
    for (int ri = 0; ri < 4; ++ri) {
      float v = acc[oi][ri] + bias;
      if (o >= 48) v *= sh;
      vals[4 * rq + ri][o] = v;
    }
  }
  __syncthreads();

  // per-row epilogue: part 0 -> e norm, 1 -> s norm, 2 -> expmap0 h + yn
  const int part = tid >> 6;
  const int row = tid & 63;
  const size_t g = (size_t)(r0 + row);
  if (part == 0) {
    float ssum = 0.0f;
    for (int j = 0; j < 32; ++j) ssum += vals[row][j] * vals[row][j];
    float nv = sqrtf(ssum);
    for (int j = 0; j < 32; ++j) ce[(size_t)j * NC + g] = vals[row][j] / nv;
  } else if (part == 1) {
    float ssum = 0.0f;
    for (int j = 32; j < 48; ++j) ssum += vals[row][j] * vals[row][j];
    float nv = sqrtf(ssum);
    for (int j = 0; j < 16; ++j) cs[(size_t)j * NC + g] = vals[row][32 + j] / nv;
  } else if (part == 2) {
    float ssum = 0.0f;
    for (int j = 48; j < 64; ++j) ssum += vals[row][j] * vals[row][j];
    float n = fmaxf(sqrtf(ssum), 1e-15f);
    float f = tanhf(n) / n;
    float yn = 0.0f;
    for (int j = 0; j < 16; ++j) {
      float hj = vals[row][48 + j] * f;
      ch[(size_t)j * NC + g] = hj;
      yn += hj * hj;
    }
    cyn[g] = yn;
  }
}

// ---------------------------------------------------------------------------
// Pairwise: each thread owns one corpus column (65 floats in regs), loops over
// a 128-query chunk; query records are wave-uniform -> scalar loads.
// out[q][c] = -(w0*dist_e + w1*dist_h + w2*dist_s)
// ---------------------------------------------------------------------------
__global__ __launch_bounds__(256) void pairwise(
    const float* __restrict__ ce, const float* __restrict__ cs,
    const float* __restrict__ ch, const float* __restrict__ cyn,
    const float* __restrict__ qrec, float* __restrict__ out)
{
  const int c = blockIdx.x * 256 + threadIdx.x;
  const int q0 = blockIdx.y * 128;

  float e[32], s[16], h[16];
  #pragma unroll
  for (int j = 0; j < 32; ++j) e[j] = ce[(size_t)j * NC + c];
  #pragma unroll
  for (int j = 0; j < 16; ++j) s[j] = cs[(size_t)j * NC + c];
  #pragma unroll
  for (int j = 0; j < 16; ++j) h[j] = ch[(size_t)j * NC + c];
  const float yn = cyn[c];

  const float CLIP = 0.99999988f;  // (float)(1.0 - 1e-7)

  for (int qi = 0; qi < 128; ++qi) {
    const float* R = qrec + (size_t)(q0 + qi) * QREC;
    float de = 0.0f, ds = 0.0f, dh = 0.0f;
    #pragma unroll
    for (int j = 0; j < 32; ++j) de = fmaf(e[j], R[j], de);
    #pragma unroll
    for (int j = 0; j < 16; ++j) ds = fmaf(s[j], R[32 + j], ds);
    #pragma unroll
    for (int j = 0; j < 16; ++j) dh = fmaf(h[j], R[48 + j], dh);
    const float xn = R[64];
    const float beta = R[65];
    const float w0 = R[66], w1 = R[67], w2 = R[68];

    // Euclidean on unit sphere
    float dist_e = 2.0f - 2.0f * de;

    // spherical
    float dcl = fminf(fmaxf(ds, -CLIP), CLIP);
    float ac = acos_poly(dcl);
    float dist_s = ac * ac;

    // hyperbolic (c=1): mirror reference fp32 op order
    float alpha = 1.0f - 2.0f * dh + yn;
    float num = alpha * alpha * xn - 2.0f * alpha * beta * dh + beta * beta * yn;
    float den = 1.0f - 2.0f * dh + xn * yn;
    den = fmaxf(den, 1e-15f);
    float t = sqrtf(fmaxf(num, 0.0f)) / den;
    t = fminf(t, CLIP);
    float dd = __logf((1.0f + t) / (1.0f - t));  // 2*artanh(t)
    float dist_h = dd * dd;

    float tot = w0 * dist_e + w1 * dist_h + w2 * dist_s;
    out[(size_t)(q0 + qi) * NC + c] = -tot;
  }
}

extern "C" void kernel_launch(void* const* d_in, const int* in_sizes, int n_in,
                              void* d_out, int out_size, void* d_ws, size_t ws_size,
                              hipStream_t stream) {
  const float* xq = (const float*)d_in[0];
  const float* xc = (const float*)d_in[1];
  const float* We = (const float*)d_in[2];
  const float* be = (const float*)d_in[3];
  const float* Wh = (const float*)d_in[4];
  const float* bh = (const float*)d_in[5];
  const float* Ws = (const float*)d_in[6];
  const float* bs = (const float*)d_in[7];
  const float* sh = (const float*)d_in[8];
  const float* W1 = (const float*)d_in[9];
  const float* b1 = (const float*)d_in[10];
  const float* W2 = (const float*)d_in[11];
  const float* b2 = (const float*)d_in[12];
  float* out = (float*)d_out;

  float* w = (float*)d_ws;
  float* qrec = w;                    // 512*72
  float* ce = qrec + NQ * QREC;       // 32*NC
  float* cs = ce + 32 * NC;           // 16*NC
  float* ch = cs + 16 * NC;           // 16*NC
  float* cyn = ch + 16 * NC;          // NC

  proj_q<<<NQ, 128, 0, stream>>>(xq, We, be, Wh, bh, Ws, bs, sh, W1, b1, W2, b2, qrec);
  proj_corpus<<<NC / 64, 256, 0, stream>>>(xc, We, be, Wh, bh, Ws, bs, sh, ce, cs, ch, cyn);
  pairwise<<<dim3(NC / 256, NQ / 128, 1), 256, 0, stream>>>(ce, cs, ch, cyn, qrec, out);
}

// Round 2
// 616.365 us; speedup vs baseline: 1.0761x; 1.0761x over previous
//
#include <hip/hip_runtime.h>
#include <math.h>

#define NQ 512
#define NC 65536
#define DIM 768
#define QREC 72
#define PC_ROWS 128

// ---------------------------------------------------------------------------
// acos via A&S 4.4.46 polynomial (|err| <= 2e-8 abs)
// ---------------------------------------------------------------------------
__device__ __forceinline__ float acos_poly(float x) {
  float z = fabsf(x);
  float p = -0.0012624911f;
  p = fmaf(p, z, 0.0066700901f);
  p = fmaf(p, z, -0.0170881256f);
  p = fmaf(p, z, 0.0308918810f);
  p = fmaf(p, z, -0.0501743046f);
  p = fmaf(p, z, 0.0889789874f);
  p = fmaf(p, z, -0.2145988016f);
  p = fmaf(p, z, 1.5707963050f);
  float r = sqrtf(1.0f - z) * p;
  return (x < 0.0f) ? (3.14159265358979f - r) : r;
}

// ---------------------------------------------------------------------------
// Transpose [We|Ws|Wh] (o-major, 768 each) into wt[768][64] (k-major) so the
// GEMM can feed W via wave-uniform s_load. Out order: 0..31 e, 32..47 s,
// 48..63 h (matches SoA consumer order).
// ---------------------------------------------------------------------------
__global__ __launch_bounds__(256) void transpose_w(
    const float* __restrict__ We, const float* __restrict__ Ws,
    const float* __restrict__ Wh, float* __restrict__ wt)
{
  int id = blockIdx.x * 256 + threadIdx.x;   // 768*64 total
  int k = id >> 6;
  int o = id & 63;
  float v = (o < 32) ? We[(size_t)o * DIM + k]
          : (o < 48) ? Ws[(size_t)(o - 32) * DIM + k]
                     : Wh[(size_t)(o - 48) * DIM + k];
  wt[id] = v;
}

// ---------------------------------------------------------------------------
// Query-side projection + softplus MLP weights. One block (128 thr) per query.
// Record layout (stride QREC=72 floats):
//   [0:32) e (unit), [32:48) s (unit), [48:64) h (expmap0),
//   [64] xn=|h|^2, [65] beta=1-xn, [66:69) w0,w1,w2
// ---------------------------------------------------------------------------
__global__ __launch_bounds__(128) void proj_q(
    const float* __restrict__ xq,
    const float* __restrict__ We, const float* __restrict__ be,
    const float* __restrict__ Wh, const float* __restrict__ bh,
    const float* __restrict__ Ws, const float* __restrict__ bs,
    const float* __restrict__ shp,
    const float* __restrict__ W1, const float* __restrict__ b1,
    const float* __restrict__ W2, const float* __restrict__ b2,
    float* __restrict__ qrec)
{
  __shared__ __align__(16) float xrow[DIM];
  __shared__ float vals[96];
  __shared__ float reluv[32];
  __shared__ float hv[16];
  __shared__ float stats[8];
  const int t = threadIdx.x;
  const int q = blockIdx.x;

  for (int i = t; i < DIM; i += 128) xrow[i] = xq[(size_t)q * DIM + i];
  __syncthreads();

  if (t < 96) {
    const float* wr;
    float bias;
    if (t < 32)      { wr = We + (size_t)t * DIM;        bias = be[t]; }
    else if (t < 48) { wr = Ws + (size_t)(t - 32) * DIM; bias = bs[t - 32]; }
    else if (t < 64) { wr = Wh + (size_t)(t - 48) * DIM; bias = bh[t - 48]; }
    else             { wr = W1 + (size_t)(t - 64) * DIM; bias = b1[t - 64]; }
    const float4* x4 = (const float4*)xrow;
    const float4* w4 = (const float4*)wr;
    float acc = 0.0f;
    #pragma unroll 4
    for (int k = 0; k < DIM / 4; ++k) {
      float4 a = x4[k];
      float4 b = w4[k];
      acc = fmaf(a.x, b.x, acc);
      acc = fmaf(a.y, b.y, acc);
      acc = fmaf(a.z, b.z, acc);
      acc = fmaf(a.w, b.w, acc);
    }
    acc += bias;
    if (t >= 48 && t < 64) acc *= shp[0];
    vals[t] = acc;
  }
  __syncthreads();
  if (t < 32) reluv[t] = fmaxf(vals[64 + t], 0.0f);
  __syncthreads();

  if (t == 0) {
    float s = 0.0f;
    for (int j = 0; j < 32; ++j) s += vals[j] * vals[j];
    stats[0] = sqrtf(s);
  } else if (t == 1) {
    float s = 0.0f;
    for (int j = 32; j < 48; ++j) s += vals[j] * vals[j];
    stats[1] = sqrtf(s);
  } else if (t == 2) {
    float s = 0.0f;
    for (int j = 48; j < 64; ++j) s += vals[j] * vals[j];
    float n = fmaxf(sqrtf(s), 1e-15f);
    float f = tanhf(n) / n;
    float xn = 0.0f;
    for (int j = 0; j < 16; ++j) {
      float hj = vals[48 + j] * f;
      hv[j] = hj;
      xn += hj * hj;
    }
    stats[2] = xn;
    stats[3] = 1.0f - xn;
  } else if (t >= 3 && t < 6) {
    int m = t - 3;
    float s = 0.0f;
    for (int j = 0; j < 32; ++j) s = fmaf(reluv[j], W2[m * 32 + j], s);
    s += b2[m];
    stats[4 + m] = fmaxf(s, 0.0f) + log1pf(expf(-fabsf(s)));
  }
  __syncthreads();

  float* rec = qrec + (size_t)q * QREC;
  if (t < 32)       rec[t] = vals[t] / stats[0];
  else if (t < 48)  rec[t] = vals[t] / stats[1];
  else if (t < 64)  rec[t] = hv[t - 48];
  else if (t == 64) rec[64] = stats[2];
  else if (t == 65) rec[65] = stats[3];
  else if (t >= 66 && t < 69) rec[t] = stats[4 + (t - 66)];
}

// ---------------------------------------------------------------------------
// Corpus projection v2: [NC,768] @ [768,64].
// Block = 512 thr (8 waves), 128 rows, all 64 outs. Each wave owns a
// wave-uniform 8-out group -> W fed via s_load (SGPR operand in v_fmac);
// LDS only stages x (transposed [k][row]) -> ds_read2_b32 per 16 FMA.
// Thread: rows {lane, lane+64} x 8 outs.
// ---------------------------------------------------------------------------
__global__ __launch_bounds__(512) void proj_corpus(
    const float* __restrict__ xc, const float* __restrict__ wt,
    const float* __restrict__ be, const float* __restrict__ bh,
    const float* __restrict__ bs, const float* __restrict__ shp,
    float* __restrict__ ce, float* __restrict__ cs,
    float* __restrict__ ch, float* __restrict__ cyn)
{
  __shared__ float lds[8320];                 // max(32*132, 128*65) floats
  float (*lxT)[132] = (float(*)[132])lds;     // [k][row] staging
  float (*vals)[65] = (float(*)[65])lds;      // [row][out] epilogue

  const int tid = threadIdx.x;
  const int lane = tid & 63;
  const int wv = __builtin_amdgcn_readfirstlane(tid >> 6); // 0..7, uniform
  const int o0 = wv * 8;
  const int r0 = blockIdx.x * PC_ROWS;

  float acc0[8], acc1[8];
  #pragma unroll
  for (int j = 0; j < 8; ++j) { acc0[j] = 0.0f; acc1[j] = 0.0f; }

  for (int k0 = 0; k0 < DIM; k0 += 32) {
    __syncthreads();  // previous chunk's reads done before overwrite
    #pragma unroll
    for (int i = 0; i < 2; ++i) {
      int p = tid + 512 * i;          // 0..1023 = 128 rows x 8 k-quads
      int row = p >> 3;
      int kq = p & 7;
      const float4 v = *(const float4*)(xc + (size_t)(r0 + row) * DIM + k0 + 4 * kq);
      lxT[4 * kq + 0][row] = v.x;
      lxT[4 * kq + 1][row] = v.y;
      lxT[4 * kq + 2][row] = v.z;
      lxT[4 * kq + 3][row] = v.w;
    }
    __syncthreads();
    #pragma unroll
    for (int k = 0; k < 32; ++k) {
      const float xv0 = lxT[k][lane];
      const float xv1 = lxT[k][lane + 64];
      const float* wk = wt + (size_t)(k0 + k) * 64 + o0;  // uniform -> s_load
      #pragma unroll
      for (int j = 0; j < 8; ++j) {
        const float w = wk[j];
        acc0[j] = fmaf(xv0, w, acc0[j]);
        acc1[j] = fmaf(xv1, w, acc1[j]);
      }
    }
  }
  __syncthreads();

  // bias + scale_h, park raw projections
  const float sh = shp[0];
  #pragma unroll
  for (int j = 0; j < 8; ++j) {
    int o = o0 + j;
    float b = (o < 32) ? be[o] : (o < 48) ? bs[o - 32] : bh[o - 48];
    float v0 = acc0[j] + b;
    float v1 = acc1[j] + b;
    if (o >= 48) { v0 *= sh; v1 *= sh; }
    vals[lane][o] = v0;
    vals[lane + 64][o] = v1;
  }
  __syncthreads();

  const int part = tid >> 7;   // 0..3 (3 idle)
  const int row = tid & 127;
  const size_t g = (size_t)(r0 + row);
  if (part == 0) {
    float ssum = 0.0f;
    for (int j = 0; j < 32; ++j) ssum += vals[row][j] * vals[row][j];
    float nv = sqrtf(ssum);
    for (int j = 0; j < 32; ++j) ce[(size_t)j * NC + g] = vals[row][j] / nv;
  } else if (part == 1) {
    float ssum = 0.0f;
    for (int j = 32; j < 48; ++j) ssum += vals[row][j] * vals[row][j];
    float nv = sqrtf(ssum);
    for (int j = 0; j < 16; ++j) cs[(size_t)j * NC + g] = vals[row][32 + j] / nv;
  } else if (part == 2) {
    float ssum = 0.0f;
    for (int j = 48; j < 64; ++j) ssum += vals[row][j] * vals[row][j];
    float n = fmaxf(sqrtf(ssum), 1e-15f);
    float f = tanhf(n) / n;
    float yn = 0.0f;
    for (int j = 0; j < 16; ++j) {
      float hj = vals[row][48 + j] * f;
      ch[(size_t)j * NC + g] = hj;
      yn += hj * hj;
    }
    cyn[g] = yn;
  }
}

// ---------------------------------------------------------------------------
// Pairwise v2: q-chunk 32 (grid.y=16 -> 16k waves demanded, resident capped
// by VGPR ~5-6/SIMD instead of grid-limited 4) + qi unrolled x2 for MLP
// across the s_load latency.
// ---------------------------------------------------------------------------
__global__ __launch_bounds__(256) void pairwise(
    const float* __restrict__ ce, const float* __restrict__ cs,
    const float* __restrict__ ch, const float* __restrict__ cyn,
    const float* __restrict__ qrec, float* __restrict__ out)
{
  const int c = blockIdx.x * 256 + threadIdx.x;
  const int q0 = blockIdx.y * 32;

  float e[32], s[16], h[16];
  #pragma unroll
  for (int j = 0; j < 32; ++j) e[j] = ce[(size_t)j * NC + c];
  #pragma unroll
  for (int j = 0; j < 16; ++j) s[j] = cs[(size_t)j * NC + c];
  #pragma unroll
  for (int j = 0; j < 16; ++j) h[j] = ch[(size_t)j * NC + c];
  const float yn = cyn[c];

  const float CLIP = 0.99999988f;  // (float)(1.0 - 1e-7)

  #pragma unroll 2
  for (int qi = 0; qi < 32; ++qi) {
    const float* R = qrec + (size_t)(q0 + qi) * QREC;
    float de = 0.0f, ds = 0.0f, dh = 0.0f;
    #pragma unroll
    for (int j = 0; j < 32; ++j) de = fmaf(e[j], R[j], de);
    #pragma unroll
    for (int j = 0; j < 16; ++j) ds = fmaf(s[j], R[32 + j], ds);
    #pragma unroll
    for (int j = 0; j < 16; ++j) dh = fmaf(h[j], R[48 + j], dh);
    const float xn = R[64];
    const float beta = R[65];
    const float w0 = R[66], w1 = R[67], w2 = R[68];

    float dist_e = 2.0f - 2.0f * de;

    float dcl = fminf(fmaxf(ds, -CLIP), CLIP);
    float ac = acos_poly(dcl);
    float dist_s = ac * ac;

    float alpha = 1.0f - 2.0f * dh + yn;
    float num = alpha * alpha * xn - 2.0f * alpha * beta * dh + beta * beta * yn;
    float den = 1.0f - 2.0f * dh + xn * yn;
    den = fmaxf(den, 1e-15f);
    float t = sqrtf(fmaxf(num, 0.0f)) / den;
    t = fminf(t, CLIP);
    float dd = __logf((1.0f + t) / (1.0f - t));
    float dist_h = dd * dd;

    float tot = w0 * dist_e + w1 * dist_h + w2 * dist_s;
    out[(size_t)(q0 + qi) * NC + c] = -tot;
  }
}

extern "C" void kernel_launch(void* const* d_in, const int* in_sizes, int n_in,
                              void* d_out, int out_size, void* d_ws, size_t ws_size,
                              hipStream_t stream) {
  const float* xq = (const float*)d_in[0];
  const float* xc = (const float*)d_in[1];
  const float* We = (const float*)d_in[2];
  const float* be = (const float*)d_in[3];
  const float* Wh = (const float*)d_in[4];
  const float* bh = (const float*)d_in[5];
  const float* Ws = (const float*)d_in[6];
  const float* bs = (const float*)d_in[7];
  const float* sh = (const float*)d_in[8];
  const float* W1 = (const float*)d_in[9];
  const float* b1 = (const float*)d_in[10];
  const float* W2 = (const float*)d_in[11];
  const float* b2 = (const float*)d_in[12];
  float* out = (float*)d_out;

  float* w = (float*)d_ws;
  float* qrec = w;                    // 512*72
  float* wt = qrec + NQ * QREC;       // 768*64
  float* ce = wt + DIM * 64;          // 32*NC
  float* cs = ce + 32 * NC;           // 16*NC
  float* ch = cs + 16 * NC;           // 16*NC
  float* cyn = ch + 16 * NC;          // NC

  transpose_w<<<DIM * 64 / 256, 256, 0, stream>>>(We, Ws, Wh, wt);
  proj_q<<<NQ, 128, 0, stream>>>(xq, We, be, Wh, bh, Ws, bs, sh, W1, b1, W2, b2, qrec);
  proj_corpus<<<NC / PC_ROWS, 512, 0, stream>>>(xc, wt, be, bh, bs, sh, ce, cs, ch, cyn);
  pairwise<<<dim3(NC / 256, NQ / 32, 1), 256, 0, stream>>>(ce, cs, ch, cyn, qrec, out);
}